// Round 2
// baseline (324.087 us; speedup 1.0000x reference)
//
#include <hip/hip_runtime.h>
#include <hip/hip_bf16.h>

#define B_    4
#define N_    16384
#define K_    16
#define CIN_  64
#define CF_   67          // 3 + 64 concat channels
#define COUT_ 128
#define AGG_  1072        // 16*67
#define AGGP_ 1088        // padded K for MFMA loop (34*32), zero-filled
#define P_    16          // points per block
#define FSTR  68          // floats per transposed feature record (272 B)
#define ASTR  1096        // aggT row stride in shorts; 548 dwords % 32 == 4
#define NEG_  0.1f

typedef __attribute__((ext_vector_type(8))) short short8;
typedef __attribute__((ext_vector_type(4))) float f32x4;

__device__ __forceinline__ short f2b(float f) {
    __hip_bfloat16 h = __float2bfloat16(f);
    return *reinterpret_cast<short*>(&h);
}
__device__ __forceinline__ float leaky(float x) { return x >= 0.f ? x : NEG_ * x; }

// ---------------------------------------------------------------------------
// Kernel 1: transpose concat(xyz, features) from [B][C][N] fp32 to
// [B][N][FSTR] fp32 so per-neighbor gathers are contiguous 268-byte records.
// ---------------------------------------------------------------------------
__global__ __launch_bounds__(256) void pc_transpose(
    const float* __restrict__ xyz,
    const float* __restrict__ feats,
    float* __restrict__ ft)
{
    __shared__ float st[64][FSTR];         // [j_local][c], 17.4 KB
    const int bid = blockIdx.x;            // B_ * (N_/64) = 1024
    const int b  = bid >> 8;
    const int j0 = (bid & 255) << 6;
    const int t  = threadIdx.x;
    const int jl = t & 63, cs = t >> 6;    // 4 c-strips

    for (int c = cs; c < CF_; c += 4) {
        const float* src = (c < 3)
            ? (xyz   + ((size_t)b * 3    + c)       * N_)
            : (feats + ((size_t)b * CIN_ + (c - 3)) * N_);
        st[jl][c] = src[j0 + jl];
    }
    __syncthreads();

    float* dst = ft + (size_t)(b * N_ + j0) * FSTR;
    for (int idx = t; idx < 64 * FSTR; idx += 256) {
        const int j2 = idx / FSTR, c = idx % FSTR;
        dst[idx] = (c < CF_) ? st[j2][c] : 0.f;
    }
}

// ---------------------------------------------------------------------------
// Kernel 2: convert lin_w fp32 [128][1072] -> bf16 [128][AGGP_] (zero-padded)
// ---------------------------------------------------------------------------
__global__ __launch_bounds__(256) void pc_cvtw(
    const float* __restrict__ lin_w, short* __restrict__ lwb)
{
    const int o = blockIdx.x;              // 128
    const float* src = lin_w + (size_t)o * AGG_;
    short*       dst = lwb   + (size_t)o * AGGP_;
    for (int c = threadIdx.x; c < AGGP_; c += 256)
        dst[c] = (c < AGG_) ? f2b(src[c]) : (short)0;
}

// ---------------------------------------------------------------------------
// Kernel 3: fused weight-net MLP + agg einsum + final linear (bf16 MFMA,
// fp32 accumulate) per 16-point tile.
// ---------------------------------------------------------------------------
__global__ __launch_bounds__(256) void pc_main(
    const float* __restrict__ ft,
    const int*   __restrict__ knn,
    const float* __restrict__ w1, const float* __restrict__ b1,
    const float* __restrict__ w2, const float* __restrict__ b2,
    const short* __restrict__ lwb, const float* __restrict__ lin_b,
    float* __restrict__ out)
{
    __shared__ float s_W[K_ * P_ * 16];    // [k][p][w]  16 KB
    __shared__ short s_aggT[P_ * ASTR];    // [p][1096] bf16, 35072 B
    __shared__ int   s_idx[P_ * K_];       // 1 KB

    const int t   = threadIdx.x;
    const int bid = blockIdx.x;            // B_ * (N_/P_) = 4096
    const int b   = bid >> 10;
    const int n0  = (bid & 1023) << 4;

    const float* ftb = ft + (size_t)b * N_ * FSTR;

    // ---------------- phase 1: weight-net MLP, one thread per (p,k) --------
    {
        const int p = t >> 4, k = t & 15;
        const int n = n0 + p;
        const int j = knn[((size_t)(b * N_ + n)) * K_ + k];
        s_idx[p * K_ + k] = j;
        const float* rj = ftb + (size_t)j * FSTR;
        const float* rn = ftb + (size_t)n * FSTR;
        const float dx0 = rj[0] - rn[0];
        const float dx1 = rj[1] - rn[1];
        const float dx2 = rj[2] - rn[2];
        float h[8];
#pragma unroll
        for (int i = 0; i < 8; i++)
            h[i] = leaky(b1[i] + w1[i*3+0]*dx0 + w1[i*3+1]*dx1 + w1[i*3+2]*dx2);
        float* dst = s_W + (k * 16 + p) * 16;
#pragma unroll
        for (int w = 0; w < 16; w++) {
            float a = b2[w];
#pragma unroll
            for (int i = 0; i < 8; i++) a += w2[w*8+i] * h[i];
            dst[w] = leaky(a);
        }
    }
    __syncthreads();

    // ---------------- phase 2: agg[w][c] = sum_k W[k][w] * F[k][c] ---------
    {
        const int p = t >> 4, s = t & 15;
        const int* idxp = s_idx + p * K_;
        const bool ok4 = (s < 3);          // c = s+64 valid only for s<3
        float acc[16][5];
#pragma unroll
        for (int w = 0; w < 16; w++)
#pragma unroll
            for (int c = 0; c < 5; c++) acc[w][c] = 0.f;

        for (int k = 0; k < K_; k++) {
            const int j = idxp[k];
            const float* rec = ftb + (size_t)j * FSTR + s;
            const float f0 = rec[0];
            const float f1 = rec[16];
            const float f2 = rec[32];
            const float f3 = rec[48];
            const float f4 = ok4 ? rec[64] : 0.f;
            const f32x4* Wk = (const f32x4*)(s_W + (k * 16 + p) * 16);
            const f32x4 wa = Wk[0], wb = Wk[1], wc = Wk[2], wd = Wk[3];
            const float wv[16] = { wa.x, wa.y, wa.z, wa.w, wb.x, wb.y, wb.z, wb.w,
                                   wc.x, wc.y, wc.z, wc.w, wd.x, wd.y, wd.z, wd.w };
#pragma unroll
            for (int w = 0; w < 16; w++) {
                acc[w][0] += wv[w] * f0;
                acc[w][1] += wv[w] * f1;
                acc[w][2] += wv[w] * f2;
                acc[w][3] += wv[w] * f3;
                acc[w][4] += wv[w] * f4;
            }
        }
        short* arow = s_aggT + p * ASTR;
#pragma unroll
        for (int w = 0; w < 16; w++) {
            arow[w * CF_ + s     ] = f2b(acc[w][0]);
            arow[w * CF_ + s + 16] = f2b(acc[w][1]);
            arow[w * CF_ + s + 32] = f2b(acc[w][2]);
            arow[w * CF_ + s + 48] = f2b(acc[w][3]);
            if (ok4) arow[w * CF_ + s + 64] = f2b(acc[w][4]);
        }
        // zero the pad region [1072, 1096) of each row
        for (int z = t; z < P_ * 24; z += 256)
            s_aggT[(z / 24) * ASTR + AGG_ + (z % 24)] = 0;
    }
    __syncthreads();

    // ---------------- phase 3: out[128 x 16] = L[128x1072] @ aggT^T --------
    {
        const int lane = t & 63, wid = t >> 6;
        const int quad = lane >> 4, pr = lane & 15;
        const int kq = quad * 8;
        // A fragment: lane holds A[m=pr][k=quad*8+j]; A row = out channel
        const short* a0p = lwb + (size_t)(wid * 32 + pr) * AGGP_ + kq;
        const short* a1p = a0p + 16 * AGGP_;
        // B fragment: lane holds B[k=quad*8+j][n=pr]; B col = point
        const short* bp  = s_aggT + pr * ASTR + kq;
        f32x4 acc0 = {0.f, 0.f, 0.f, 0.f};
        f32x4 acc1 = {0.f, 0.f, 0.f, 0.f};

#pragma unroll 2
        for (int ks = 0; ks < 34; ks++) {
            const int k = ks * 32;
            const short8 bfr = *(const short8*)(bp + k);
            const short8 a0  = *(const short8*)(a0p + k);
            const short8 a1  = *(const short8*)(a1p + k);
            acc0 = __builtin_amdgcn_mfma_f32_16x16x32_bf16(a0, bfr, acc0, 0, 0, 0);
            acc1 = __builtin_amdgcn_mfma_f32_16x16x32_bf16(a1, bfr, acc1, 0, 0, 0);
        }
        // epilogue: D row = quad*4 + r (out channel within tile), D col = pr
        const int o0 = wid * 32 + quad * 4;
#pragma unroll
        for (int r = 0; r < 4; r++) {
            const int oA = o0 + r;
            const int oB = oA + 16;
            const float vA = leaky(acc0[r] + lin_b[oA]);
            const float vB = leaky(acc1[r] + lin_b[oB]);
            out[((size_t)(b * COUT_ + oA)) * N_ + n0 + pr] = vA;
            out[((size_t)(b * COUT_ + oB)) * N_ + n0 + pr] = vB;
        }
    }
}

extern "C" void kernel_launch(void* const* d_in, const int* in_sizes, int n_in,
                              void* d_out, int out_size, void* d_ws, size_t ws_size,
                              hipStream_t stream)
{
    const float* xyz   = (const float*)d_in[0];
    const float* feats = (const float*)d_in[1];
    const int*   knn   = (const int*)d_in[2];
    const float* w1    = (const float*)d_in[3];
    const float* b1    = (const float*)d_in[4];
    const float* w2    = (const float*)d_in[5];
    const float* b2    = (const float*)d_in[6];
    const float* lin_w = (const float*)d_in[7];
    const float* lin_b = (const float*)d_in[8];
    float* out = (float*)d_out;

    float* ft  = (float*)d_ws;                          // [B][N][FSTR] fp32, 17.8 MB
    short* lwb = (short*)((char*)d_ws + (size_t)B_ * N_ * FSTR * sizeof(float));
                                                        // [128][AGGP_] bf16, 272 KB

    hipLaunchKernelGGL(pc_transpose, dim3(B_ * (N_ / 64)), dim3(256), 0, stream,
                       xyz, feats, ft);
    hipLaunchKernelGGL(pc_cvtw, dim3(COUT_), dim3(256), 0, stream, lin_w, lwb);
    hipLaunchKernelGGL(pc_main, dim3(B_ * (N_ / P_)), dim3(256), 0, stream,
                       ft, knn, w1, b1, w2, b2, lwb, lin_b, out);
}